// Round 7
// baseline (272.908 us; speedup 1.0000x reference)
//
#include <hip/hip_runtime.h>
#include <hip/hip_cooperative_groups.h>

namespace cg = cooperative_groups;

// Problem constants (B=1 fixed)
#define RR     1024
#define NSEQ   128
#define CFEAT  22
#define CMSA   256
#define CPAIR  128
#define NBINS  65
#define PPB    64   // (n,r) pairs per msa role-unit
#define NUNITS 4096 // 2048 pair units + 2048 msa units, 8-interleaved

typedef float f4 __attribute__((ext_vector_type(4)));
typedef float f2 __attribute__((ext_vector_type(2)));

// ---------------------------------------------------------------------------
// Single cooperative kernel.
// Phase A (blocks 0..127): per-residue projections a/bv/tm2 + pose table.
//   Weight columns per-thread from global (no big LDS; 45 KB/block L2 reads).
// grid.sync()  (device-scope release+acquire -> cross-XCD visibility)
// Phase B (all blocks, grid-stride over 4096 role-units, 8-block groups):
//   pair unit: z[i,j,c] = a[j,c]+bv[i,c]+pose[bin(i,j)][c], NT f4 stores
//              (R4/R6 A/B: plain stores cost +29 us, intrinsic to L2 path).
//   msa unit : m[n,r,c] = msa@Wm1.T + bm1 + tm2[r,:], weights in registers
//              (2 ch/thread), NT f2 stores.
// ---------------------------------------------------------------------------
__global__ __launch_bounds__(256, 8) void k_all(
    const float* __restrict__ tf, const int* __restrict__ resi,
    const float* __restrict__ msa,
    const float* __restrict__ Wa, const float* __restrict__ ba,
    const float* __restrict__ Wb, const float* __restrict__ bb,
    const float* __restrict__ Wm1, const float* __restrict__ bm1,
    const float* __restrict__ Wm2, const float* __restrict__ bm2,
    const float* __restrict__ Wpos, const float* __restrict__ bpos,
    float* __restrict__ a, float* __restrict__ bvp,
    float* __restrict__ tm2, float* __restrict__ pose,
    float* __restrict__ out_z, float* __restrict__ out_m)
{
    __shared__ union U {
        float rows8[8][CFEAT];               // pre: 704 B
        struct { int rj[512]; } p;           // pair: 2 KB
        struct { float rows[PPB][24]; } m;   // msa: 6 KB
    } sm;
    const int t = threadIdx.x;
    const int b = blockIdx.x;

    // ---------------- Phase A: pre ----------------
    if (b < 128) {
        const int r0 = b * 8;
        for (int idx = t; idx < 8 * CFEAT; idx += 256)
            sm.rows8[idx / CFEAT][idx % CFEAT] = tf[r0 * CFEAT + idx];
        __syncthreads();

        float w1[CFEAT], w2[CFEAT];
        const float* wp1 = (t < CPAIR) ? (Wa + t * CFEAT)
                                       : (Wb + (t - CPAIR) * CFEAT);
        const float* wp2 = Wm2 + t * CFEAT;
        #pragma unroll
        for (int k = 0; k < CFEAT; ++k) { w1[k] = wp1[k]; w2[k] = wp2[k]; }
        const float bias1 = (t < CPAIR) ? ba[t] : bb[t - CPAIR];
        const float bias2 = bm2[t];

        #pragma unroll
        for (int rr = 0; rr < 8; ++rr) {
            float s1 = 0.f, s2 = 0.f;
            #pragma unroll
            for (int k = 0; k < CFEAT; ++k) {
                const float rv = sm.rows8[rr][k];
                s1 += rv * w1[k];
                s2 += rv * w2[k];
            }
            const int r = r0 + rr;
            tm2[r * CMSA + t] = s2 + bias2;
            if (t < CPAIR) a[r * CPAIR + t] = s1 + bias1;
            else           bvp[r * CPAIR + (t - CPAIR)] = s1 + bias1;
        }
    }
    if (b < NBINS && t < CPAIR)
        pose[b * CPAIR + t] = Wpos[t * NBINS + b] + bpos[t];

    cg::this_grid().sync();

    // ---------------- Phase B: grid-stride over role-units ----------------
    for (int u = b; u < NUNITS; u += gridDim.x) {
        __syncthreads();  // protect LDS reuse across unit iterations
        const int grp = u >> 3, sub = u & 7;
        const int id = (grp >> 1) * 8 + sub;  // role-local unit id, 0..2047

        if ((grp & 1) == 0) {
            // ---------------- pair unit: half-row of z ----------------
            const int i = id >> 1;
            const int jbase = (id & 1) * 512;
            for (int idx = t; idx < 512; idx += 256)
                sm.p.rj[idx] = resi[jbase + idx];
            __syncthreads();

            const int c4 = (t & 31) * 4;  // channel base 0,4,...,124
            const int jo = t >> 5;        // 0..7
            const int ri = resi[i];
            const f4 bvv = *(const f4*)(bvp + (long)i * CPAIR + c4);
            float* dst = out_z + ((long)i * RR + jbase) * CPAIR;

            #pragma unroll 4
            for (int jj = 0; jj < 512; jj += 8) {
                const int jl = jj + jo;
                int d = sm.p.rj[jl] - ri + (NBINS / 2);
                d = min(max(d, 0), NBINS - 1);
                const f4 av = *(const f4*)(a + (long)(jbase + jl) * CPAIR + c4);
                const f4 pv = *(const f4*)(pose + (long)d * CPAIR + c4);
                f4 o = av + bvv + pv;
                __builtin_nontemporal_store(o, (f4*)(dst + (long)jl * CPAIR + c4));
            }
        } else {
            // ---------------- msa unit: 64 pairs of m ----------------
            const long pbase = (long)id * PPB;
            const float* src = msa + pbase * CFEAT;
            for (int idx = t; idx < PPB * CFEAT; idx += 256) {
                int p = idx / CFEAT, k = idx - p * CFEAT;
                sm.m.rows[p][k] = src[idx];
            }
            if (t < PPB) { sm.m.rows[t][22] = 0.f; sm.m.rows[t][23] = 0.f; }

            const int c2 = (t & 127) * 2;  // channels c2, c2+1
            const int ps = t >> 7;         // pair slot parity 0/1
            float wA[24], wB[24];
            const float* wp = Wm1 + (long)c2 * CFEAT;
            #pragma unroll
            for (int k = 0; k < CFEAT; ++k) { wA[k] = wp[k]; wB[k] = wp[CFEAT + k]; }
            wA[22] = wA[23] = wB[22] = wB[23] = 0.f;
            const float b0 = bm1[c2], b1 = bm1[c2 + 1];
            __syncthreads();

            for (int it = 0; it < PPB / 2; ++it) {
                const int p = it * 2 + ps;
                const long pair = pbase + p;
                const int r = (int)(pair & (RR - 1));
                float a0 = 0.f, a1 = 0.f;
                #pragma unroll
                for (int k4 = 0; k4 < 6; ++k4) {
                    f4 mv = *(const f4*)&sm.m.rows[p][k4 * 4];
                    a0 += mv.x * wA[k4 * 4 + 0]; a1 += mv.x * wB[k4 * 4 + 0];
                    a0 += mv.y * wA[k4 * 4 + 1]; a1 += mv.y * wB[k4 * 4 + 1];
                    a0 += mv.z * wA[k4 * 4 + 2]; a1 += mv.z * wB[k4 * 4 + 2];
                    a0 += mv.w * wA[k4 * 4 + 3]; a1 += mv.w * wB[k4 * 4 + 3];
                }
                const f2 t2 = *(const f2*)(tm2 + (long)r * CMSA + c2);
                f2 o;
                o.x = a0 + b0 + t2.x;
                o.y = a1 + b1 + t2.y;
                __builtin_nontemporal_store(o, (f2*)(out_m + pair * CMSA + c2));
            }
        }
    }
}

// ---------------------------------------------------------------------------
extern "C" void kernel_launch(void* const* d_in, const int* in_sizes, int n_in,
                              void* d_out, int out_size, void* d_ws, size_t ws_size,
                              hipStream_t stream) {
    const float* tf   = (const float*)d_in[0];
    const int*   resi = (const int*)  d_in[1];
    const float* msa  = (const float*)d_in[2];
    const float* Wa   = (const float*)d_in[3];
    const float* ba   = (const float*)d_in[4];
    const float* Wb   = (const float*)d_in[5];
    const float* bb   = (const float*)d_in[6];
    const float* Wm1  = (const float*)d_in[7];
    const float* bm1  = (const float*)d_in[8];
    const float* Wm2  = (const float*)d_in[9];
    const float* bm2  = (const float*)d_in[10];
    const float* Wpos = (const float*)d_in[11];
    const float* bpos = (const float*)d_in[12];

    float* out_m = (float*)d_out;                        // 128*1024*256
    float* out_z = out_m + (long)NSEQ * RR * CMSA;       // 1024*1024*128

    // workspace layout (floats): a | bv | tm2 | pose  (~2.13 MB total)
    float* a    = (float*)d_ws;
    float* bvp  = a   + (long)RR * CPAIR;
    float* tm2  = bvp + (long)RR * CPAIR;
    float* pose = tm2 + (long)RR * CMSA;

    // co-resident grid for cooperative launch (deterministic each call)
    int occ = 8;
    (void)hipOccupancyMaxActiveBlocksPerMultiprocessor(&occ, (const void*)k_all,
                                                       256, 0);
    int grid = occ * 256;           // 256 CUs on MI355X
    if (grid > 2048) grid = 2048;   // 8 blocks/CU upper bound we designed for
    if (grid > NUNITS) grid = NUNITS;

    void* args[] = {
        (void*)&tf, (void*)&resi, (void*)&msa,
        (void*)&Wa, (void*)&ba, (void*)&Wb, (void*)&bb,
        (void*)&Wm1, (void*)&bm1, (void*)&Wm2, (void*)&bm2,
        (void*)&Wpos, (void*)&bpos,
        (void*)&a, (void*)&bvp, (void*)&tm2, (void*)&pose,
        (void*)&out_z, (void*)&out_m,
    };
    (void)hipLaunchCooperativeKernel((const void*)k_all, dim3(grid), dim3(256),
                                     args, 0, stream);
}

// Round 8
// 156.128 us; speedup vs baseline: 1.7480x; 1.7480x over previous
//
#include <hip/hip_runtime.h>

// Problem constants (B=1 fixed)
#define RR     1024
#define NSEQ   128
#define CFEAT  22
#define CMSA   256
#define CPAIR  128
#define NBINS  65

typedef float f4 __attribute__((ext_vector_type(4)));
typedef float f2 __attribute__((ext_vector_type(2)));

// z-store experiment: sc1 (bypass L2, allocate in memory-side L3) instead of
// nt (no-allocate everywhere). R4/R6 showed plain (L2-allocate) = +30us;
// R3/R5 nt = 4.9 TB/s vs 6.6 TB/s fill calibration.
static __device__ __forceinline__ void store_sc1(float* p, f4 v) {
    asm volatile("global_store_dwordx4 %0, %1, off sc1"
                 :: "v"(p), "v"(v) : "memory");
}

// ---------------------------------------------------------------------------
// Kernel 1: per-residue projections + relpos table (128 blocks x 8 rows)
// ---------------------------------------------------------------------------
__global__ __launch_bounds__(256) void k_pre(
    const float* __restrict__ tf,
    const float* __restrict__ Wa, const float* __restrict__ ba,
    const float* __restrict__ Wb, const float* __restrict__ bb,
    const float* __restrict__ Wm2, const float* __restrict__ bm2,
    const float* __restrict__ Wpos, const float* __restrict__ bpos,
    float* __restrict__ a, float* __restrict__ bvp,
    float* __restrict__ tm2, float* __restrict__ pose)
{
    __shared__ float wlds[CFEAT][512];
    __shared__ float rows[8][CFEAT];
    const int t = threadIdx.x;
    const int r0 = blockIdx.x * 8;

    for (int idx = t; idx < 128 * CFEAT; idx += 256) {
        int c = idx / CFEAT, k = idx - c * CFEAT;
        wlds[k][c] = Wa[idx];
    }
    for (int idx = t; idx < 128 * CFEAT; idx += 256) {
        int c = idx / CFEAT, k = idx - c * CFEAT;
        wlds[k][128 + c] = Wb[idx];
    }
    for (int idx = t; idx < 256 * CFEAT; idx += 256) {
        int c = idx / CFEAT, k = idx - c * CFEAT;
        wlds[k][256 + c] = Wm2[idx];
    }
    for (int idx = t; idx < 8 * CFEAT; idx += 256) {
        int rr = idx / CFEAT, k = idx - rr * CFEAT;
        rows[rr][k] = tf[(r0 + rr) * CFEAT + k];
    }
    __syncthreads();

    #pragma unroll
    for (int rr = 0; rr < 8; ++rr) {
        const int r = r0 + rr;
        float s1 = 0.f, s2 = 0.f;
        #pragma unroll
        for (int k = 0; k < CFEAT; ++k) {
            float rv = rows[rr][k];
            s1 += rv * wlds[k][t];        // a (t<128) or bv (t>=128)
            s2 += rv * wlds[k][256 + t];  // tm2
        }
        tm2[r * CMSA + t] = s2 + bm2[t];
        if (t < CPAIR) a[r * CPAIR + t] = s1 + ba[t];
        else           bvp[r * CPAIR + (t - CPAIR)] = s1 + bb[t - CPAIR];
    }

    if (blockIdx.x < NBINS && t < CPAIR)
        pose[blockIdx.x * CPAIR + t] = Wpos[t * NBINS + blockIdx.x] + bpos[t];
}

// ---------------------------------------------------------------------------
// Fused kernel: block-role split (per 8-block group).
//   pair role (2048 blocks): z = a[j]+bv[i]+pose[bin], sc1 f4 stores (A/B).
//   msa role  (2048 blocks): m = msa@Wm1.T + bm1 + tm2, 2 ch/thread weights
//                            in registers, NT f2 stores.
// ---------------------------------------------------------------------------
#define PPB 64  // (n,r) pairs per msa block

__global__ __launch_bounds__(256, 8) void k_fused(
    const int* __restrict__ resi,
    const float* __restrict__ a, const float* __restrict__ bvp,
    const float* __restrict__ pose, float* __restrict__ out_z,
    const float* __restrict__ msa,
    const float* __restrict__ Wm1, const float* __restrict__ bm1,
    const float* __restrict__ tm2, float* __restrict__ out_m)
{
    __shared__ union U {
        struct { float rows[PPB][24]; } m;  // 6 KB
        struct { int rj[512]; } p;          // 2 KB
    } sm;
    const int bx = blockIdx.x;
    const int grp = bx >> 3, sub = bx & 7;
    const int id = (grp >> 1) * 8 + sub;   // role-local block id, 0..2047
    const int t = threadIdx.x;

    if ((grp & 1) == 0) {
        // ---------------- pair role ----------------
        const int i = id >> 1;                 // row 0..1023
        const int jbase = (id & 1) * 512;      // half-row
        for (int idx = t; idx < 512; idx += 256)
            sm.p.rj[idx] = resi[jbase + idx];
        __syncthreads();

        const int c4 = (t & 31) * 4;  // channel base 0,4,...,124
        const int jo = t >> 5;        // 0..7
        const int ri = resi[i];
        const f4 bvv = *(const f4*)(bvp + (long)i * CPAIR + c4);
        float* dst = out_z + ((long)i * RR + jbase) * CPAIR;

        #pragma unroll 4
        for (int jj = 0; jj < 512; jj += 8) {
            const int jl = jj + jo;
            int d = sm.p.rj[jl] - ri + (NBINS / 2);
            d = min(max(d, 0), NBINS - 1);
            const f4 av = *(const f4*)(a + (long)(jbase + jl) * CPAIR + c4);
            const f4 pv = *(const f4*)(pose + (long)d * CPAIR + c4);
            f4 o = av + bvv + pv;
            store_sc1(dst + (long)jl * CPAIR + c4, o);   // sc1 store (A/B)
        }
    } else {
        // ---------------- msa role ----------------
        const long pbase = (long)id * PPB;
        const float* src = msa + pbase * CFEAT;
        for (int idx = t; idx < PPB * CFEAT; idx += 256) {
            int p = idx / CFEAT, k = idx - p * CFEAT;
            sm.m.rows[p][k] = src[idx];
        }
        if (t < PPB) { sm.m.rows[t][22] = 0.f; sm.m.rows[t][23] = 0.f; }

        // per-thread weights: 2 channels, 24 padded k each
        const int c2 = (t & 127) * 2;  // channels c2, c2+1
        const int ps = t >> 7;         // pair slot parity 0/1
        float wA[24], wB[24];
        const float* wp = Wm1 + (long)c2 * CFEAT;
        #pragma unroll
        for (int k = 0; k < CFEAT; ++k) { wA[k] = wp[k]; wB[k] = wp[CFEAT + k]; }
        wA[22] = wA[23] = wB[22] = wB[23] = 0.f;
        const float b0 = bm1[c2], b1 = bm1[c2 + 1];
        __syncthreads();

        for (int it = 0; it < PPB / 2; ++it) {
            const int p = it * 2 + ps;            // half-block-uniform slot
            const long pair = pbase + p;
            const int r = (int)(pair & (RR - 1)); // pair % 1024
            float a0 = 0.f, a1 = 0.f;
            #pragma unroll
            for (int k4 = 0; k4 < 6; ++k4) {
                f4 mv = *(const f4*)&sm.m.rows[p][k4 * 4];  // broadcast b128
                a0 += mv.x * wA[k4 * 4 + 0]; a1 += mv.x * wB[k4 * 4 + 0];
                a0 += mv.y * wA[k4 * 4 + 1]; a1 += mv.y * wB[k4 * 4 + 1];
                a0 += mv.z * wA[k4 * 4 + 2]; a1 += mv.z * wB[k4 * 4 + 2];
                a0 += mv.w * wA[k4 * 4 + 3]; a1 += mv.w * wB[k4 * 4 + 3];
            }
            const f2 t2 = *(const f2*)(tm2 + (long)r * CMSA + c2);
            f2 o;
            o.x = a0 + b0 + t2.x;
            o.y = a1 + b1 + t2.y;
            __builtin_nontemporal_store(o, (f2*)(out_m + pair * CMSA + c2));
        }
    }
}

// ---------------------------------------------------------------------------
extern "C" void kernel_launch(void* const* d_in, const int* in_sizes, int n_in,
                              void* d_out, int out_size, void* d_ws, size_t ws_size,
                              hipStream_t stream) {
    const float* tf   = (const float*)d_in[0];
    const int*   resi = (const int*)  d_in[1];
    const float* msa  = (const float*)d_in[2];
    const float* Wa   = (const float*)d_in[3];
    const float* ba   = (const float*)d_in[4];
    const float* Wb   = (const float*)d_in[5];
    const float* bb   = (const float*)d_in[6];
    const float* Wm1  = (const float*)d_in[7];
    const float* bm1  = (const float*)d_in[8];
    const float* Wm2  = (const float*)d_in[9];
    const float* bm2  = (const float*)d_in[10];
    const float* Wpos = (const float*)d_in[11];
    const float* bpos = (const float*)d_in[12];

    float* out_m = (float*)d_out;                        // 128*1024*256
    float* out_z = out_m + (long)NSEQ * RR * CMSA;       // 1024*1024*128

    // workspace layout (floats): a | bv | tm2 | pose  (~2.13 MB total)
    float* a    = (float*)d_ws;
    float* bvp  = a   + (long)RR * CPAIR;
    float* tm2  = bvp + (long)RR * CPAIR;
    float* pose = tm2 + (long)RR * CMSA;

    k_pre<<<128, 256, 0, stream>>>(tf, Wa, ba, Wb, bb, Wm2, bm2, Wpos, bpos,
                                   a, bvp, tm2, pose);
    k_fused<<<4096, 256, 0, stream>>>(resi, a, bvp, pose, out_z,
                                      msa, Wm1, bm1, tm2, out_m);
}